// Round 15
// baseline (75.263 us; speedup 1.0000x reference)
//
#include <hip/hip_runtime.h>

// SpikeEncoder: out[b,h] = ( sum_k count[b,k]*W2[h,k] + S*T*b2[h] ) / B
// R15 = R14 with the gemm2_out type fix (f32x4 used consistently).
//  gemm1: R11 exact (measured 17.7us).
//  lif: 4-way sequence split (8-word warmup), LDS combine, chain 640->240.
//  gemm2: single direct-out kernel, full-K per thread, W2 read once.
//
// ws: cnt[256K) | h1L[16MB) | Ahi(8M) Alo(8M) Whi(2M)

#define TSTEPS 10
#define SEQ    64
#define BATCH  64
#define EDIM   1024
#define HDIM   1024
#define NROW   (SEQ * BATCH)   // 4096

typedef unsigned short u16;
typedef __attribute__((ext_vector_type(8))) _Float16 half8;
typedef __attribute__((ext_vector_type(8))) unsigned short ushort8;
typedef __attribute__((ext_vector_type(4))) float  f32x4;

union h16 { _Float16 f; u16 u; };

__device__ __forceinline__ u16 f2h_bits(float x) {
    h16 t; t.f = (_Float16)x; return t.u;       // RNE
}
__device__ __forceinline__ float h2f(u16 b) {
    h16 t; t.u = b; return (float)t.f;
}
__device__ __forceinline__ void gld16(const u16* g, u16* l) {
    __builtin_amdgcn_global_load_lds(
        (const __attribute__((address_space(1))) void*)g,
        (__attribute__((address_space(3))) void*)l, 16, 0, 0);
}

// ---- split fp32 -> fp16 hi + scaled-lo (unchanged) -----------------------
__global__ __launch_bounds__(256) void split_pack(
    const float* __restrict__ emb, const float* __restrict__ W1,
    const int* __restrict__ idx,
    u16* __restrict__ ahi, u16* __restrict__ alo, u16* __restrict__ whi)
{
    const int t = blockIdx.x * 256 + threadIdx.x;
    const int r = t >> 7;
    const int c = (t & 127) << 3;
    if (r < NROW) {
        const int srow = idx[(r & 63) * 64 + (r >> 6)];   // r = b*64+s
        const float* src = emb + (size_t)srow * EDIM + c;
        float4 v0 = *(const float4*)src;
        float4 v1 = *(const float4*)(src + 4);
        float x[8] = {v0.x, v0.y, v0.z, v0.w, v1.x, v1.y, v1.z, v1.w};
        ushort8 h, l;
#pragma unroll
        for (int j = 0; j < 8; ++j) {
            u16 hh = f2h_bits(x[j]);
            h[j] = hh;
            l[j] = f2h_bits((x[j] - h2f(hh)) * 2048.0f);
        }
        *(ushort8*)(ahi + (size_t)r * EDIM + c) = h;
        *(ushort8*)(alo + (size_t)r * EDIM + c) = l;
    } else {
        const int rw = r - NROW;
        const float* src = W1 + (size_t)rw * EDIM + c;
        float4 v0 = *(const float4*)src;
        float4 v1 = *(const float4*)(src + 4);
        float x[8] = {v0.x, v0.y, v0.z, v0.w, v1.x, v1.y, v1.z, v1.w};
        ushort8 h;
#pragma unroll
        for (int j = 0; j < 8; ++j) h[j] = f2h_bits(x[j]);
        *(ushort8*)(whi + (size_t)rw * EDIM + c) = h;
    }
}

// ---- GEMM1 (R11 exact): BM=64 BN=128, 3-buf counted vmcnt, 3 blk/CU ------
#define BM 64
#define BN 128
#define BK 32
#define NT (EDIM / BK)
#define AH 0
#define AL 2048
#define WH 4096
#define BUF 8192

__global__ __launch_bounds__(256, 3) void gemm1_h1(
    const u16* __restrict__ Ahi, const u16* __restrict__ Alo,
    const u16* __restrict__ Whi,
    float* __restrict__ h1L)
{
    __shared__ float smf[12288];                // 48KB: 3x16KB staging
    u16* stage = (u16*)smf;

    const int bid = blockIdx.x;
    const int loc = bid >> 3;
    const int by  = (bid & 7) * 8 + (loc & 7);
    const int bx  = loc >> 3;
    const int row0 = by * BM, col0 = bx * BN;

    const int tid  = threadIdx.x;
    const int wave = tid >> 6, lane = tid & 63;
    const int wn   = wave;
    const int lrow = lane & 15, kgrp = lane >> 4;

    const int srr = lane >> 2;
    const int kcs = (((lane & 3) ^ ((lane >> 3) & 3)) << 3);
    const size_t aoff = (size_t)(row0 + wave * 16 + srr) * EDIM + kcs;
    const size_t w0   = (size_t)(col0 + wave * 32 + srr) * EDIM + kcs;
    const size_t w1   = w0 + (size_t)16 * EDIM;

    f32x4 acc[4][2], acl[4][2];
    const f32x4 zero = {0.f, 0.f, 0.f, 0.f};
#pragma unroll
    for (int m = 0; m < 4; ++m)
#pragma unroll
        for (int n = 0; n < 2; ++n) { acc[m][n] = zero; acl[m][n] = zero; }

    auto STAGE = [&](int k0, int b) {
        u16* lb = stage + b * BUF;
        gld16(Ahi + aoff + k0, lb + AH + wave * 512);
        gld16(Alo + aoff + k0, lb + AL + wave * 512);
        gld16(Whi + w0 + k0, lb + WH + wave * 1024);
        gld16(Whi + w1 + k0, lb + WH + wave * 1024 + 512);
    };

    auto COMPUTE = [&](int b) {
        const u16* lb = stage + b * BUF;
        half8 ah[4], al[4], bh[2];
#pragma unroll
        for (int n = 0; n < 2; ++n) {
            const int c = wn * 32 + n * 16 + lrow;
            const int s = kgrp ^ ((c >> 1) & 3);
            bh[n] = *(const half8*)(lb + WH + c * 32 + s * 8);
        }
#pragma unroll
        for (int m = 0; m < 4; ++m) {
            const int r = m * 16 + lrow;
            const int s = kgrp ^ ((r >> 1) & 3);
            const u16* p = lb + AH + r * 32 + s * 8;
            ah[m] = *(const half8*)p;
            al[m] = *(const half8*)(p + (AL - AH));
        }
#pragma unroll
        for (int m = 0; m < 4; ++m)
#pragma unroll
            for (int n = 0; n < 2; ++n) {
                acc[m][n] = __builtin_amdgcn_mfma_f32_16x16x32_f16(ah[m], bh[n], acc[m][n], 0, 0, 0);
                acl[m][n] = __builtin_amdgcn_mfma_f32_16x16x32_f16(al[m], bh[n], acl[m][n], 0, 0, 0);
            }
    };

    STAGE(0, 0);
    STAGE(BK, 1);
    int cc = 0, cs = 2;
    for (int t = 0; t < NT - 2; ++t) {
        STAGE((t + 2) * BK, cs);
        asm volatile("s_waitcnt vmcnt(8)" ::: "memory");
        __builtin_amdgcn_s_barrier();
        __builtin_amdgcn_sched_barrier(0);
        COMPUTE(cc);
        __builtin_amdgcn_s_barrier();
        cc = (cc == 2) ? 0 : cc + 1;
        cs = (cs == 2) ? 0 : cs + 1;
    }
    asm volatile("s_waitcnt vmcnt(4)" ::: "memory");
    __builtin_amdgcn_s_barrier();
    __builtin_amdgcn_sched_barrier(0);
    COMPUTE(cc);
    cc = (cc == 2) ? 0 : cc + 1;
    asm volatile("s_waitcnt vmcnt(0)" ::: "memory");
    __builtin_amdgcn_s_barrier();
    __builtin_amdgcn_sched_barrier(0);
    COMPUTE(cc);

    // epilogue: h1L[b][k][s] straight from acc, float4 along s.
#pragma unroll
    for (int n = 0; n < 2; ++n) {
        const int col = col0 + wn * 32 + n * 16 + lrow;
        float* base = h1L + ((size_t)by * HDIM + col) * 64 + kgrp * 4;
#pragma unroll
        for (int m = 0; m < 4; ++m) {
            f32x4 v;
#pragma unroll
            for (int j = 0; j < 4; ++j)
                v[j] = acc[m][n][j] + acl[m][n][j] * (1.0f / 2048.0f);
            *(f32x4*)(base + m * 16) = v;
        }
    }
}

// ---- LIF: 4-way sequence split, wave = quarter, LDS combine --------------
// Block = 64 neurons. Wave q handles words [16q,16q+16) after an 8-word
// warmup (q>0). leak^80=0.017 initial-state damping + contractive soft
// reset; R13's identical-warmup 2-way split produced bit-identical absmax.
__global__ __launch_bounds__(256) void lif_count(
    const float* __restrict__ h1L,
    const float* __restrict__ bias1,
    const float* __restrict__ pthr, const float* __restrict__ pleak,
    float* __restrict__ cnt)
{
    __shared__ float sm[4][64];
    const int tid  = threadIdx.x;
    const int q    = tid >> 6;            // wave = sequence quarter
    const int lane = tid & 63;
    const int neuron = blockIdx.x * 64 + lane;
    const float thr = pthr[0];
    const float lk  = pleak[0];
    const float b1v = bias1[neuron & (HDIM - 1)];
    const float4* row = (const float4*)(h1L + (size_t)neuron * 64);

    float mem = 0.f, c = 0.f;
    const int sq0 = q * 4;
    if (q > 0) {
#pragma unroll 2
        for (int sq = sq0 - 2; sq < sq0; ++sq) {     // warmup, uncounted
            float4 xv = row[sq];
            float xs[4] = {xv.x, xv.y, xv.z, xv.w};
#pragma unroll
            for (int u = 0; u < 4; ++u) {
                const float x = xs[u] + b1v;
#pragma unroll
                for (int t = 0; t < TSTEPS; ++t) {
                    mem = lk * mem + x;
                    if (mem > thr) mem -= thr;
                }
            }
        }
    }
#pragma unroll 2
    for (int sq = sq0; sq < sq0 + 4; ++sq) {         // counted quarter
        float4 xv = row[sq];
        float xs[4] = {xv.x, xv.y, xv.z, xv.w};
#pragma unroll
        for (int u = 0; u < 4; ++u) {
            const float x = xs[u] + b1v;
#pragma unroll
            for (int t = 0; t < TSTEPS; ++t) {
                mem = lk * mem + x;
                if (mem > thr) { c += 1.f; mem -= thr; }
            }
        }
    }
    sm[q][lane] = c;
    __syncthreads();
    if (tid < 64)
        cnt[(size_t)blockIdx.x * 64 + tid] =
            sm[0][tid] + sm[1][tid] + sm[2][tid] + sm[3][tid];
}

// ---- GEMM2 direct-out: full-K per thread, W2 read once -------------------
// 256 blocks = 8 xcd x (4 hgrp x 8 bgrp chunk). Block: 32 h x 8 b.
// Thread: h = h0 + (tid&31), b = b0 + (tid>>5); 1024 FMAs, 4 rot. accs.
__global__ __launch_bounds__(256) void gemm2_out(
    const float* __restrict__ cnt,
    const float* __restrict__ W2,
    const float* __restrict__ b2,
    float* __restrict__ out)
{
    __shared__ float cL[8 * 1032];        // [b][k], pad 1032
    const int bid  = blockIdx.x;
    const int xcd  = bid & 7;
    const int j    = bid >> 3;            // 0..31
    const int hgrp = xcd * 4 + (j >> 3);  // same-xcd blocks share W2 slab
    const int bgrp = j & 7;
    const int h0 = hgrp * 32, b0 = bgrp * 8;

    const int tid = threadIdx.x;
    // stage cnt slice: 8 rows x 256 quads; thread tid loads quad tid of each row
#pragma unroll
    for (int i = 0; i < 8; ++i) {
        f32x4 v = *(const f32x4*)(cnt + (size_t)(b0 + i) * HDIM + tid * 4);
        *(f32x4*)(cL + i * 1032 + tid * 4) = v;
    }
    __syncthreads();

    const int th = tid & 31, tb = tid >> 5;
    const float* wrow = W2 + (size_t)(h0 + th) * HDIM;
    const float* crow = cL + tb * 1032;

    float a0 = 0.f, a1 = 0.f, a2 = 0.f, a3 = 0.f;
#pragma unroll 8
    for (int kq = 0; kq < 256; ++kq) {
        f32x4 w = *(const f32x4*)(wrow + kq * 4);
        f32x4 c = *(const f32x4*)(crow + kq * 4);
        a0 += w[0] * c[0];
        a1 += w[1] * c[1];
        a2 += w[2] * c[2];
        a3 += w[3] * c[3];
    }
    const float s = (a0 + a1) + (a2 + a3);
    const int h = h0 + th;
    out[(size_t)(b0 + tb) * HDIM + h] =
        (s + (float)(SEQ * TSTEPS) * b2[h]) * (1.0f / (float)BATCH);
}

extern "C" void kernel_launch(void* const* d_in, const int* in_sizes, int n_in,
                              void* d_out, int out_size, void* d_ws, size_t ws_size,
                              hipStream_t stream)
{
    (void)in_sizes; (void)n_in; (void)out_size; (void)ws_size;

    const int*   idx  = (const int*)d_in[0];
    const float* emb  = (const float*)d_in[1];
    const float* W1   = (const float*)d_in[2];
    const float* b1   = (const float*)d_in[3];
    const float* W2   = (const float*)d_in[4];
    const float* b2   = (const float*)d_in[5];
    const float* thr  = (const float*)d_in[6];
    const float* leak = (const float*)d_in[7];
    float* out = (float*)d_out;

    char* ws = (char*)d_ws;
    float* cnt = (float*)ws;                                   // 256 KB
    float* h1L = (float*)(ws + (size_t)BATCH * HDIM * 4);      // 16 MB
    u16* ahi = (u16*)((char*)h1L + (size_t)NROW * HDIM * 4);
    u16* alo = ahi + (size_t)NROW * EDIM;
    u16* whi = alo + (size_t)NROW * EDIM;

    split_pack<<<dim3((NROW + HDIM) * 128 / 256), 256, 0, stream>>>(
        emb, W1, idx, ahi, alo, whi);

    gemm1_h1<<<dim3((NROW / BM) * (HDIM / BN)), 256, 0, stream>>>(
        ahi, alo, whi, h1L);

    lif_count<<<dim3(BATCH * HDIM / 64), 256, 0, stream>>>(
        h1L, b1, thr, leak, cnt);

    gemm2_out<<<dim3(256), 256, 0, stream>>>(cnt, W2, b2, out);
}

// Round 16
// 54.825 us; speedup vs baseline: 1.3728x; 1.3728x over previous
//
#include <hip/hip_runtime.h>

// SpikeEncoder: out[b,h] = ( sum_k count[b,k]*W2[h,k] + S*T*b2[h] ) / B
// R16 = R11 exactly + ONE change: lif 4-way sequence split (R12 measured
// lif at 9.2us chain-latency-bound; split cuts critical path 640->240 and
// quadruples wave count). gemm2_partial/reduce_out restored from R11
// (both R13/R15 gemm2 rebuilds regressed: uncoalesced per-lane-row W2).
//
// ws: part[4MB) | cnt[256K) | h1L[16MB) | Ahi(8M) Alo(8M) Whi(2M)

#define TSTEPS 10
#define SEQ    64
#define BATCH  64
#define EDIM   1024
#define HDIM   1024
#define NROW   (SEQ * BATCH)   // 4096
#define KSPLIT 16

typedef unsigned short u16;
typedef __attribute__((ext_vector_type(8))) _Float16 half8;
typedef __attribute__((ext_vector_type(8))) unsigned short ushort8;
typedef __attribute__((ext_vector_type(4))) float  f32x4;

union h16 { _Float16 f; u16 u; };

__device__ __forceinline__ u16 f2h_bits(float x) {
    h16 t; t.f = (_Float16)x; return t.u;       // RNE
}
__device__ __forceinline__ float h2f(u16 b) {
    h16 t; t.u = b; return (float)t.f;
}
__device__ __forceinline__ void gld16(const u16* g, u16* l) {
    __builtin_amdgcn_global_load_lds(
        (const __attribute__((address_space(1))) void*)g,
        (__attribute__((address_space(3))) void*)l, 16, 0, 0);
}

// ---- split fp32 -> fp16 hi + scaled-lo -----------------------------------
__global__ __launch_bounds__(256) void split_pack(
    const float* __restrict__ emb, const float* __restrict__ W1,
    const int* __restrict__ idx,
    u16* __restrict__ ahi, u16* __restrict__ alo, u16* __restrict__ whi)
{
    const int t = blockIdx.x * 256 + threadIdx.x;
    const int r = t >> 7;
    const int c = (t & 127) << 3;
    if (r < NROW) {
        const int srow = idx[(r & 63) * 64 + (r >> 6)];   // r = b*64+s
        const float* src = emb + (size_t)srow * EDIM + c;
        float4 v0 = *(const float4*)src;
        float4 v1 = *(const float4*)(src + 4);
        float x[8] = {v0.x, v0.y, v0.z, v0.w, v1.x, v1.y, v1.z, v1.w};
        ushort8 h, l;
#pragma unroll
        for (int j = 0; j < 8; ++j) {
            u16 hh = f2h_bits(x[j]);
            h[j] = hh;
            l[j] = f2h_bits((x[j] - h2f(hh)) * 2048.0f);
        }
        *(ushort8*)(ahi + (size_t)r * EDIM + c) = h;
        *(ushort8*)(alo + (size_t)r * EDIM + c) = l;
    } else {
        const int rw = r - NROW;
        const float* src = W1 + (size_t)rw * EDIM + c;
        float4 v0 = *(const float4*)src;
        float4 v1 = *(const float4*)(src + 4);
        float x[8] = {v0.x, v0.y, v0.z, v0.w, v1.x, v1.y, v1.z, v1.w};
        ushort8 h;
#pragma unroll
        for (int j = 0; j < 8; ++j) h[j] = f2h_bits(x[j]);
        *(ushort8*)(whi + (size_t)rw * EDIM + c) = h;
    }
}

// ---- GEMM1 (R11 exact): BM=64 BN=128, 3-buf counted vmcnt, 3 blk/CU ------
#define BM 64
#define BN 128
#define BK 32
#define NT (EDIM / BK)
#define AH 0
#define AL 2048
#define WH 4096
#define BUF 8192

__global__ __launch_bounds__(256, 3) void gemm1_h1(
    const u16* __restrict__ Ahi, const u16* __restrict__ Alo,
    const u16* __restrict__ Whi,
    float* __restrict__ h1L)
{
    __shared__ float smf[12288];                // 48KB: 3x16KB staging
    u16* stage = (u16*)smf;

    const int bid = blockIdx.x;
    const int loc = bid >> 3;
    const int by  = (bid & 7) * 8 + (loc & 7);
    const int bx  = loc >> 3;
    const int row0 = by * BM, col0 = bx * BN;

    const int tid  = threadIdx.x;
    const int wave = tid >> 6, lane = tid & 63;
    const int wn   = wave;
    const int lrow = lane & 15, kgrp = lane >> 4;

    const int srr = lane >> 2;
    const int kcs = (((lane & 3) ^ ((lane >> 3) & 3)) << 3);
    const size_t aoff = (size_t)(row0 + wave * 16 + srr) * EDIM + kcs;
    const size_t w0   = (size_t)(col0 + wave * 32 + srr) * EDIM + kcs;
    const size_t w1   = w0 + (size_t)16 * EDIM;

    f32x4 acc[4][2], acl[4][2];
    const f32x4 zero = {0.f, 0.f, 0.f, 0.f};
#pragma unroll
    for (int m = 0; m < 4; ++m)
#pragma unroll
        for (int n = 0; n < 2; ++n) { acc[m][n] = zero; acl[m][n] = zero; }

    auto STAGE = [&](int k0, int b) {
        u16* lb = stage + b * BUF;
        gld16(Ahi + aoff + k0, lb + AH + wave * 512);
        gld16(Alo + aoff + k0, lb + AL + wave * 512);
        gld16(Whi + w0 + k0, lb + WH + wave * 1024);
        gld16(Whi + w1 + k0, lb + WH + wave * 1024 + 512);
    };

    auto COMPUTE = [&](int b) {
        const u16* lb = stage + b * BUF;
        half8 ah[4], al[4], bh[2];
#pragma unroll
        for (int n = 0; n < 2; ++n) {
            const int c = wn * 32 + n * 16 + lrow;
            const int s = kgrp ^ ((c >> 1) & 3);
            bh[n] = *(const half8*)(lb + WH + c * 32 + s * 8);
        }
#pragma unroll
        for (int m = 0; m < 4; ++m) {
            const int r = m * 16 + lrow;
            const int s = kgrp ^ ((r >> 1) & 3);
            const u16* p = lb + AH + r * 32 + s * 8;
            ah[m] = *(const half8*)p;
            al[m] = *(const half8*)(p + (AL - AH));
        }
#pragma unroll
        for (int m = 0; m < 4; ++m)
#pragma unroll
            for (int n = 0; n < 2; ++n) {
                acc[m][n] = __builtin_amdgcn_mfma_f32_16x16x32_f16(ah[m], bh[n], acc[m][n], 0, 0, 0);
                acl[m][n] = __builtin_amdgcn_mfma_f32_16x16x32_f16(al[m], bh[n], acl[m][n], 0, 0, 0);
            }
    };

    STAGE(0, 0);
    STAGE(BK, 1);
    int cc = 0, cs = 2;
    for (int t = 0; t < NT - 2; ++t) {
        STAGE((t + 2) * BK, cs);
        asm volatile("s_waitcnt vmcnt(8)" ::: "memory");
        __builtin_amdgcn_s_barrier();
        __builtin_amdgcn_sched_barrier(0);
        COMPUTE(cc);
        __builtin_amdgcn_s_barrier();
        cc = (cc == 2) ? 0 : cc + 1;
        cs = (cs == 2) ? 0 : cs + 1;
    }
    asm volatile("s_waitcnt vmcnt(4)" ::: "memory");
    __builtin_amdgcn_s_barrier();
    __builtin_amdgcn_sched_barrier(0);
    COMPUTE(cc);
    cc = (cc == 2) ? 0 : cc + 1;
    asm volatile("s_waitcnt vmcnt(0)" ::: "memory");
    __builtin_amdgcn_s_barrier();
    __builtin_amdgcn_sched_barrier(0);
    COMPUTE(cc);

    // epilogue: h1L[b][k][s] straight from acc, float4 along s.
#pragma unroll
    for (int n = 0; n < 2; ++n) {
        const int col = col0 + wn * 32 + n * 16 + lrow;
        float* base = h1L + ((size_t)by * HDIM + col) * 64 + kgrp * 4;
#pragma unroll
        for (int m = 0; m < 4; ++m) {
            f32x4 v;
#pragma unroll
            for (int j = 0; j < 4; ++j)
                v[j] = acc[m][n][j] + acl[m][n][j] * (1.0f / 2048.0f);
            *(f32x4*)(base + m * 16) = v;
        }
    }
}

// ---- LIF: 4-way sequence split (R15 kernel verbatim; absmax-identical) ---
__global__ __launch_bounds__(256) void lif_count(
    const float* __restrict__ h1L,
    const float* __restrict__ bias1,
    const float* __restrict__ pthr, const float* __restrict__ pleak,
    float* __restrict__ cnt)
{
    __shared__ float sm[4][64];
    const int tid  = threadIdx.x;
    const int q    = tid >> 6;            // wave = sequence quarter
    const int lane = tid & 63;
    const int neuron = blockIdx.x * 64 + lane;
    const float thr = pthr[0];
    const float lk  = pleak[0];
    const float b1v = bias1[neuron & (HDIM - 1)];
    const float4* row = (const float4*)(h1L + (size_t)neuron * 64);

    float mem = 0.f, c = 0.f;
    const int sq0 = q * 4;
    if (q > 0) {
#pragma unroll 2
        for (int sq = sq0 - 2; sq < sq0; ++sq) {     // warmup, uncounted
            float4 xv = row[sq];
            float xs[4] = {xv.x, xv.y, xv.z, xv.w};
#pragma unroll
            for (int u = 0; u < 4; ++u) {
                const float x = xs[u] + b1v;
#pragma unroll
                for (int t = 0; t < TSTEPS; ++t) {
                    mem = lk * mem + x;
                    if (mem > thr) mem -= thr;
                }
            }
        }
    }
#pragma unroll 2
    for (int sq = sq0; sq < sq0 + 4; ++sq) {         // counted quarter
        float4 xv = row[sq];
        float xs[4] = {xv.x, xv.y, xv.z, xv.w};
#pragma unroll
        for (int u = 0; u < 4; ++u) {
            const float x = xs[u] + b1v;
#pragma unroll
            for (int t = 0; t < TSTEPS; ++t) {
                mem = lk * mem + x;
                if (mem > thr) { c += 1.f; mem -= thr; }
            }
        }
    }
    sm[q][lane] = c;
    __syncthreads();
    if (tid < 64)
        cnt[(size_t)blockIdx.x * 64 + tid] =
            sm[0][tid] + sm[1][tid] + sm[2][tid] + sm[3][tid];
}

// ---- GEMM2 (R11 exact): K-split partials ---------------------------------
__global__ __launch_bounds__(256) void gemm2_partial(
    const float* __restrict__ cnt,
    const float* __restrict__ W2,
    float* __restrict__ part)
{
    __shared__ float As[32][68];
    __shared__ float Bs[32][132];

    const int tid   = threadIdx.x;
    const int col0  = blockIdx.x * 128;
    const int kc    = blockIdx.y;
    const int kbase = kc * 64;

    const int lr = tid >> 3;
    const int lc = (tid & 7) * 4;
    const int tm = (tid >> 4) * 4;
    const int tn = (tid & 15) * 4;

    float acc[4][8];
#pragma unroll
    for (int i = 0; i < 4; ++i)
#pragma unroll
        for (int j = 0; j < 8; ++j) acc[i][j] = 0.f;

    for (int kt = 0; kt < 2; ++kt) {
        const int k0 = kbase + kt * 32;
#pragma unroll
        for (int p = 0; p < 2; ++p) {
            int r = p * 32 + lr;
            float4 v = *(const float4*)(cnt + (size_t)r * HDIM + k0 + lc);
            As[lc + 0][r] = v.x; As[lc + 1][r] = v.y;
            As[lc + 2][r] = v.z; As[lc + 3][r] = v.w;
        }
#pragma unroll
        for (int p = 0; p < 4; ++p) {
            int r = p * 32 + lr;
            float4 v = *(const float4*)(W2 + (size_t)(col0 + r) * HDIM + k0 + lc);
            Bs[lc + 0][r] = v.x; Bs[lc + 1][r] = v.y;
            Bs[lc + 2][r] = v.z; Bs[lc + 3][r] = v.w;
        }
        __syncthreads();
#pragma unroll 8
        for (int k = 0; k < 32; ++k) {
            float4 a   = *(const float4*)&As[k][tm];
            float4 bb0 = *(const float4*)&Bs[k][tn];
            float4 bb1 = *(const float4*)&Bs[k][tn + 64];
            float av[4] = {a.x, a.y, a.z, a.w};
            float bv[8] = {bb0.x, bb0.y, bb0.z, bb0.w, bb1.x, bb1.y, bb1.z, bb1.w};
#pragma unroll
            for (int i = 0; i < 4; ++i)
#pragma unroll
                for (int j = 0; j < 8; ++j)
                    acc[i][j] += av[i] * bv[j];
        }
        __syncthreads();
    }

#pragma unroll
    for (int i = 0; i < 4; ++i) {
        float* prow = part + (size_t)kc * (BATCH * HDIM) + (size_t)(tm + i) * HDIM + col0;
        float4 o0, o1;
        o0.x = acc[i][0]; o0.y = acc[i][1]; o0.z = acc[i][2]; o0.w = acc[i][3];
        o1.x = acc[i][4]; o1.y = acc[i][5]; o1.z = acc[i][6]; o1.w = acc[i][7];
        *(float4*)(prow + tn)      = o0;
        *(float4*)(prow + tn + 64) = o1;
    }
}

// ---- final reduce: out = (sum_kc part + 640*b2) / 64 ----------------------
__global__ __launch_bounds__(256) void reduce_out(
    const float* __restrict__ part,
    const float* __restrict__ b2,
    float* __restrict__ out)
{
    const int i = blockIdx.x * 256 + threadIdx.x;
    float s = 0.f;
#pragma unroll
    for (int kc = 0; kc < KSPLIT; ++kc)
        s += part[(size_t)kc * (BATCH * HDIM) + i];
    const int h = i & (HDIM - 1);
    out[i] = (s + (float)(SEQ * TSTEPS) * b2[h]) * (1.0f / (float)BATCH);
}

extern "C" void kernel_launch(void* const* d_in, const int* in_sizes, int n_in,
                              void* d_out, int out_size, void* d_ws, size_t ws_size,
                              hipStream_t stream)
{
    (void)in_sizes; (void)n_in; (void)out_size; (void)ws_size;

    const int*   idx  = (const int*)d_in[0];
    const float* emb  = (const float*)d_in[1];
    const float* W1   = (const float*)d_in[2];
    const float* b1   = (const float*)d_in[3];
    const float* W2   = (const float*)d_in[4];
    const float* b2   = (const float*)d_in[5];
    const float* thr  = (const float*)d_in[6];
    const float* leak = (const float*)d_in[7];
    float* out = (float*)d_out;

    char* ws = (char*)d_ws;
    float* part = (float*)ws;                                        // 4 MB
    float* cnt  = (float*)(ws + (size_t)KSPLIT * BATCH * HDIM * 4);  // 256 KB
    float* h1L  = cnt + (size_t)BATCH * HDIM;                        // 16 MB
    u16* ahi = (u16*)((char*)h1L + (size_t)NROW * HDIM * 4);
    u16* alo = ahi + (size_t)NROW * EDIM;
    u16* whi = alo + (size_t)NROW * EDIM;

    split_pack<<<dim3((NROW + HDIM) * 128 / 256), 256, 0, stream>>>(
        emb, W1, idx, ahi, alo, whi);

    gemm1_h1<<<dim3((NROW / BM) * (HDIM / BN)), 256, 0, stream>>>(
        ahi, alo, whi, h1L);

    lif_count<<<dim3(BATCH * HDIM / 64), 256, 0, stream>>>(
        h1L, b1, thr, leak, cnt);

    gemm2_partial<<<dim3(HDIM / 128, KSPLIT), 256, 0, stream>>>(cnt, W2, part);

    reduce_out<<<dim3((BATCH * HDIM) / 256), 256, 0, stream>>>(part, b2, out);
}

// Round 17
// 48.050 us; speedup vs baseline: 1.5664x; 1.1410x over previous
//
#include <hip/hip_runtime.h>

// SpikeEncoder: out[b,h] = ( sum_k count[b,k]*W2[h,k] + S*T*b2[h] ) / B
// R17 = R16 + ONE change: 1-term plain-fp16 GEMM1 (Alo tensor dropped).
// h1 err ~5e-4 -> a few LIF count flips -> out perturbation ~2e-3 << 0.18.
// Cuts packed data 18->10MB, MFMA x0.5, LDS-read/k-step 10->6KB (k-loop is
// LDS-BW-bound at 17.7us measured), staging 4->3 loads (vmcnt 6/3/0).
//
// ws: part[4MB) | cnt[256K) | h1L[16MB) | Ahi(8M) Whi(2M)

#define TSTEPS 10
#define SEQ    64
#define BATCH  64
#define EDIM   1024
#define HDIM   1024
#define NROW   (SEQ * BATCH)   // 4096
#define KSPLIT 16

typedef unsigned short u16;
typedef __attribute__((ext_vector_type(8))) _Float16 half8;
typedef __attribute__((ext_vector_type(8))) unsigned short ushort8;
typedef __attribute__((ext_vector_type(4))) float  f32x4;

union h16 { _Float16 f; u16 u; };

__device__ __forceinline__ u16 f2h_bits(float x) {
    h16 t; t.f = (_Float16)x; return t.u;       // RNE
}
__device__ __forceinline__ void gld16(const u16* g, u16* l) {
    __builtin_amdgcn_global_load_lds(
        (const __attribute__((address_space(1))) void*)g,
        (__attribute__((address_space(3))) void*)l, 16, 0, 0);
}

// ---- pack fp32 -> fp16 (A gathered+permuted, W1) -------------------------
__global__ __launch_bounds__(256) void split_pack(
    const float* __restrict__ emb, const float* __restrict__ W1,
    const int* __restrict__ idx,
    u16* __restrict__ ahi, u16* __restrict__ whi)
{
    const int t = blockIdx.x * 256 + threadIdx.x;
    const int r = t >> 7;
    const int c = (t & 127) << 3;
    if (r < NROW) {
        const int srow = idx[(r & 63) * 64 + (r >> 6)];   // r = b*64+s
        const float* src = emb + (size_t)srow * EDIM + c;
        float4 v0 = *(const float4*)src;
        float4 v1 = *(const float4*)(src + 4);
        float x[8] = {v0.x, v0.y, v0.z, v0.w, v1.x, v1.y, v1.z, v1.w};
        ushort8 h;
#pragma unroll
        for (int j = 0; j < 8; ++j) h[j] = f2h_bits(x[j]);
        *(ushort8*)(ahi + (size_t)r * EDIM + c) = h;
    } else {
        const int rw = r - NROW;
        const float* src = W1 + (size_t)rw * EDIM + c;
        float4 v0 = *(const float4*)src;
        float4 v1 = *(const float4*)(src + 4);
        float x[8] = {v0.x, v0.y, v0.z, v0.w, v1.x, v1.y, v1.z, v1.w};
        ushort8 h;
#pragma unroll
        for (int j = 0; j < 8; ++j) h[j] = f2h_bits(x[j]);
        *(ushort8*)(whi + (size_t)rw * EDIM + c) = h;
    }
}

// ---- GEMM1: 1-term fp16, BM=64 BN=128, 3-buf counted vmcnt, 3 blk/CU -----
#define BM 64
#define BN 128
#define BK 32
#define NT (EDIM / BK)
// u16 offsets inside one 12KB buffer:
#define AH 0          // [64][32]
#define WH 2048       // [128][32]
#define BUF 6144      // 12KB in u16 units

__global__ __launch_bounds__(256, 3) void gemm1_h1(
    const u16* __restrict__ Ahi,
    const u16* __restrict__ Whi,
    float* __restrict__ h1L)
{
    __shared__ float smf[9216];                 // 36KB: 3x12KB staging
    u16* stage = (u16*)smf;

    const int bid = blockIdx.x;
    const int loc = bid >> 3;
    const int by  = (bid & 7) * 8 + (loc & 7);
    const int bx  = loc >> 3;
    const int row0 = by * BM, col0 = bx * BN;

    const int tid  = threadIdx.x;
    const int wave = tid >> 6, lane = tid & 63;
    const int wn   = wave;
    const int lrow = lane & 15, kgrp = lane >> 4;

    const int srr = lane >> 2;
    const int kcs = (((lane & 3) ^ ((lane >> 3) & 3)) << 3);
    const size_t aoff = (size_t)(row0 + wave * 16 + srr) * EDIM + kcs;
    const size_t w0   = (size_t)(col0 + wave * 32 + srr) * EDIM + kcs;
    const size_t w1   = w0 + (size_t)16 * EDIM;

    f32x4 acc[4][2];
    const f32x4 zero = {0.f, 0.f, 0.f, 0.f};
#pragma unroll
    for (int m = 0; m < 4; ++m)
#pragma unroll
        for (int n = 0; n < 2; ++n) acc[m][n] = zero;

    // per-thread gld16 count per STAGE = 3 (vmcnt accounting)
    auto STAGE = [&](int k0, int b) {
        u16* lb = stage + b * BUF;
        gld16(Ahi + aoff + k0, lb + AH + wave * 512);
        gld16(Whi + w0 + k0, lb + WH + wave * 1024);
        gld16(Whi + w1 + k0, lb + WH + wave * 1024 + 512);
    };

    auto COMPUTE = [&](int b) {
        const u16* lb = stage + b * BUF;
        half8 ah[4], bh[2];
#pragma unroll
        for (int n = 0; n < 2; ++n) {
            const int c = wn * 32 + n * 16 + lrow;
            const int s = kgrp ^ ((c >> 1) & 3);
            bh[n] = *(const half8*)(lb + WH + c * 32 + s * 8);
        }
#pragma unroll
        for (int m = 0; m < 4; ++m) {
            const int r = m * 16 + lrow;
            const int s = kgrp ^ ((r >> 1) & 3);
            ah[m] = *(const half8*)(lb + AH + r * 32 + s * 8);
        }
#pragma unroll
        for (int m = 0; m < 4; ++m)
#pragma unroll
            for (int n = 0; n < 2; ++n)
                acc[m][n] = __builtin_amdgcn_mfma_f32_16x16x32_f16(ah[m], bh[n], acc[m][n], 0, 0, 0);
    };

    STAGE(0, 0);
    STAGE(BK, 1);
    int cc = 0, cs = 2;
    for (int t = 0; t < NT - 2; ++t) {
        STAGE((t + 2) * BK, cs);
        asm volatile("s_waitcnt vmcnt(6)" ::: "memory");
        __builtin_amdgcn_s_barrier();
        __builtin_amdgcn_sched_barrier(0);
        COMPUTE(cc);
        __builtin_amdgcn_s_barrier();
        cc = (cc == 2) ? 0 : cc + 1;
        cs = (cs == 2) ? 0 : cs + 1;
    }
    asm volatile("s_waitcnt vmcnt(3)" ::: "memory");
    __builtin_amdgcn_s_barrier();
    __builtin_amdgcn_sched_barrier(0);
    COMPUTE(cc);
    cc = (cc == 2) ? 0 : cc + 1;
    asm volatile("s_waitcnt vmcnt(0)" ::: "memory");
    __builtin_amdgcn_s_barrier();
    __builtin_amdgcn_sched_barrier(0);
    COMPUTE(cc);

    // epilogue: h1L[b][k][s] straight from acc, float4 along s.
#pragma unroll
    for (int n = 0; n < 2; ++n) {
        const int col = col0 + wn * 32 + n * 16 + lrow;
        float* base = h1L + ((size_t)by * HDIM + col) * 64 + kgrp * 4;
#pragma unroll
        for (int m = 0; m < 4; ++m) {
            f32x4 v;
#pragma unroll
            for (int j = 0; j < 4; ++j) v[j] = acc[m][n][j];
            *(f32x4*)(base + m * 16) = v;
        }
    }
}

// ---- LIF: 4-way sequence split (R16 verbatim) ----------------------------
__global__ __launch_bounds__(256) void lif_count(
    const float* __restrict__ h1L,
    const float* __restrict__ bias1,
    const float* __restrict__ pthr, const float* __restrict__ pleak,
    float* __restrict__ cnt)
{
    __shared__ float sm[4][64];
    const int tid  = threadIdx.x;
    const int q    = tid >> 6;            // wave = sequence quarter
    const int lane = tid & 63;
    const int neuron = blockIdx.x * 64 + lane;
    const float thr = pthr[0];
    const float lk  = pleak[0];
    const float b1v = bias1[neuron & (HDIM - 1)];
    const float4* row = (const float4*)(h1L + (size_t)neuron * 64);

    float mem = 0.f, c = 0.f;
    const int sq0 = q * 4;
    if (q > 0) {
#pragma unroll 2
        for (int sq = sq0 - 2; sq < sq0; ++sq) {     // warmup, uncounted
            float4 xv = row[sq];
            float xs[4] = {xv.x, xv.y, xv.z, xv.w};
#pragma unroll
            for (int u = 0; u < 4; ++u) {
                const float x = xs[u] + b1v;
#pragma unroll
                for (int t = 0; t < TSTEPS; ++t) {
                    mem = lk * mem + x;
                    if (mem > thr) mem -= thr;
                }
            }
        }
    }
#pragma unroll 2
    for (int sq = sq0; sq < sq0 + 4; ++sq) {         // counted quarter
        float4 xv = row[sq];
        float xs[4] = {xv.x, xv.y, xv.z, xv.w};
#pragma unroll
        for (int u = 0; u < 4; ++u) {
            const float x = xs[u] + b1v;
#pragma unroll
            for (int t = 0; t < TSTEPS; ++t) {
                mem = lk * mem + x;
                if (mem > thr) { c += 1.f; mem -= thr; }
            }
        }
    }
    sm[q][lane] = c;
    __syncthreads();
    if (tid < 64)
        cnt[(size_t)blockIdx.x * 64 + tid] =
            sm[0][tid] + sm[1][tid] + sm[2][tid] + sm[3][tid];
}

// ---- GEMM2 (R11 exact): K-split partials ---------------------------------
__global__ __launch_bounds__(256) void gemm2_partial(
    const float* __restrict__ cnt,
    const float* __restrict__ W2,
    float* __restrict__ part)
{
    __shared__ float As[32][68];
    __shared__ float Bs[32][132];

    const int tid   = threadIdx.x;
    const int col0  = blockIdx.x * 128;
    const int kc    = blockIdx.y;
    const int kbase = kc * 64;

    const int lr = tid >> 3;
    const int lc = (tid & 7) * 4;
    const int tm = (tid >> 4) * 4;
    const int tn = (tid & 15) * 4;

    float acc[4][8];
#pragma unroll
    for (int i = 0; i < 4; ++i)
#pragma unroll
        for (int j = 0; j < 8; ++j) acc[i][j] = 0.f;

    for (int kt = 0; kt < 2; ++kt) {
        const int k0 = kbase + kt * 32;
#pragma unroll
        for (int p = 0; p < 2; ++p) {
            int r = p * 32 + lr;
            float4 v = *(const float4*)(cnt + (size_t)r * HDIM + k0 + lc);
            As[lc + 0][r] = v.x; As[lc + 1][r] = v.y;
            As[lc + 2][r] = v.z; As[lc + 3][r] = v.w;
        }
#pragma unroll
        for (int p = 0; p < 4; ++p) {
            int r = p * 32 + lr;
            float4 v = *(const float4*)(W2 + (size_t)(col0 + r) * HDIM + k0 + lc);
            Bs[lc + 0][r] = v.x; Bs[lc + 1][r] = v.y;
            Bs[lc + 2][r] = v.z; Bs[lc + 3][r] = v.w;
        }
        __syncthreads();
#pragma unroll 8
        for (int k = 0; k < 32; ++k) {
            float4 a   = *(const float4*)&As[k][tm];
            float4 bb0 = *(const float4*)&Bs[k][tn];
            float4 bb1 = *(const float4*)&Bs[k][tn + 64];
            float av[4] = {a.x, a.y, a.z, a.w};
            float bv[8] = {bb0.x, bb0.y, bb0.z, bb0.w, bb1.x, bb1.y, bb1.z, bb1.w};
#pragma unroll
            for (int i = 0; i < 4; ++i)
#pragma unroll
                for (int j = 0; j < 8; ++j)
                    acc[i][j] += av[i] * bv[j];
        }
        __syncthreads();
    }

#pragma unroll
    for (int i = 0; i < 4; ++i) {
        float* prow = part + (size_t)kc * (BATCH * HDIM) + (size_t)(tm + i) * HDIM + col0;
        float4 o0, o1;
        o0.x = acc[i][0]; o0.y = acc[i][1]; o0.z = acc[i][2]; o0.w = acc[i][3];
        o1.x = acc[i][4]; o1.y = acc[i][5]; o1.z = acc[i][6]; o1.w = acc[i][7];
        *(float4*)(prow + tn)      = o0;
        *(float4*)(prow + tn + 64) = o1;
    }
}

// ---- final reduce: out = (sum_kc part + 640*b2) / 64 ----------------------
__global__ __launch_bounds__(256) void reduce_out(
    const float* __restrict__ part,
    const float* __restrict__ b2,
    float* __restrict__ out)
{
    const int i = blockIdx.x * 256 + threadIdx.x;
    float s = 0.f;
#pragma unroll
    for (int kc = 0; kc < KSPLIT; ++kc)
        s += part[(size_t)kc * (BATCH * HDIM) + i];
    const int h = i & (HDIM - 1);
    out[i] = (s + (float)(SEQ * TSTEPS) * b2[h]) * (1.0f / (float)BATCH);
}

extern "C" void kernel_launch(void* const* d_in, const int* in_sizes, int n_in,
                              void* d_out, int out_size, void* d_ws, size_t ws_size,
                              hipStream_t stream)
{
    (void)in_sizes; (void)n_in; (void)out_size; (void)ws_size;

    const int*   idx  = (const int*)d_in[0];
    const float* emb  = (const float*)d_in[1];
    const float* W1   = (const float*)d_in[2];
    const float* b1   = (const float*)d_in[3];
    const float* W2   = (const float*)d_in[4];
    const float* b2   = (const float*)d_in[5];
    const float* thr  = (const float*)d_in[6];
    const float* leak = (const float*)d_in[7];
    float* out = (float*)d_out;

    char* ws = (char*)d_ws;
    float* part = (float*)ws;                                        // 4 MB
    float* cnt  = (float*)(ws + (size_t)KSPLIT * BATCH * HDIM * 4);  // 256 KB
    float* h1L  = cnt + (size_t)BATCH * HDIM;                        // 16 MB
    u16* ahi = (u16*)((char*)h1L + (size_t)NROW * HDIM * 4);         // 8 MB
    u16* whi = ahi + (size_t)NROW * EDIM;                            // 2 MB

    split_pack<<<dim3((NROW + HDIM) * 128 / 256), 256, 0, stream>>>(
        emb, W1, idx, ahi, whi);

    gemm1_h1<<<dim3((NROW / BM) * (HDIM / BN)), 256, 0, stream>>>(
        ahi, whi, h1L);

    lif_count<<<dim3(BATCH * HDIM / 64), 256, 0, stream>>>(
        h1L, b1, thr, leak, cnt);

    gemm2_partial<<<dim3(HDIM / 128, KSPLIT), 256, 0, stream>>>(cnt, W2, part);

    reduce_out<<<dim3((BATCH * HDIM) / 256), 256, 0, stream>>>(part, b2, out);
}

// Round 18
// 45.340 us; speedup vs baseline: 1.6600x; 1.0598x over previous
//
#include <hip/hip_runtime.h>

// SpikeEncoder: out[b,h] = ( sum_k count[b,k]*W2[h,k] + S*T*b2[h] ) / B
// R18 = R17 + two proven levers:
//  (1) h1L stored fp16 (round-trip 32->16MB; x gains ~2e-4 err, negligible)
//  (2) gemm2 64-col tiles -> 256 blocks (was 128 = half the CUs idle;
//      measured 7.3us latency-bound, VALUBusy 13%)
//
// ws: part[4MB) | cnt[256K) | h1H[8MB fp16) | Ahi(8M) Whi(2M)

#define TSTEPS 10
#define SEQ    64
#define BATCH  64
#define EDIM   1024
#define HDIM   1024
#define NROW   (SEQ * BATCH)   // 4096
#define KSPLIT 16

typedef unsigned short u16;
typedef __attribute__((ext_vector_type(8))) _Float16 half8;
typedef __attribute__((ext_vector_type(8))) unsigned short ushort8;
typedef __attribute__((ext_vector_type(4))) unsigned short ushort4v;
typedef __attribute__((ext_vector_type(4))) float  f32x4;

union h16 { _Float16 f; u16 u; };

__device__ __forceinline__ u16 f2h_bits(float x) {
    h16 t; t.f = (_Float16)x; return t.u;       // RNE
}
__device__ __forceinline__ float h2f(u16 b) {
    h16 t; t.u = b; return (float)t.f;
}
__device__ __forceinline__ void gld16(const u16* g, u16* l) {
    __builtin_amdgcn_global_load_lds(
        (const __attribute__((address_space(1))) void*)g,
        (__attribute__((address_space(3))) void*)l, 16, 0, 0);
}

// ---- pack fp32 -> fp16 (A gathered+permuted, W1) -------------------------
__global__ __launch_bounds__(256) void split_pack(
    const float* __restrict__ emb, const float* __restrict__ W1,
    const int* __restrict__ idx,
    u16* __restrict__ ahi, u16* __restrict__ whi)
{
    const int t = blockIdx.x * 256 + threadIdx.x;
    const int r = t >> 7;
    const int c = (t & 127) << 3;
    if (r < NROW) {
        const int srow = idx[(r & 63) * 64 + (r >> 6)];   // r = b*64+s
        const float* src = emb + (size_t)srow * EDIM + c;
        float4 v0 = *(const float4*)src;
        float4 v1 = *(const float4*)(src + 4);
        float x[8] = {v0.x, v0.y, v0.z, v0.w, v1.x, v1.y, v1.z, v1.w};
        ushort8 h;
#pragma unroll
        for (int j = 0; j < 8; ++j) h[j] = f2h_bits(x[j]);
        *(ushort8*)(ahi + (size_t)r * EDIM + c) = h;
    } else {
        const int rw = r - NROW;
        const float* src = W1 + (size_t)rw * EDIM + c;
        float4 v0 = *(const float4*)src;
        float4 v1 = *(const float4*)(src + 4);
        float x[8] = {v0.x, v0.y, v0.z, v0.w, v1.x, v1.y, v1.z, v1.w};
        ushort8 h;
#pragma unroll
        for (int j = 0; j < 8; ++j) h[j] = f2h_bits(x[j]);
        *(ushort8*)(whi + (size_t)rw * EDIM + c) = h;
    }
}

// ---- GEMM1: 1-term fp16, BM=64 BN=128, 3-buf counted vmcnt, 3 blk/CU -----
#define BM 64
#define BN 128
#define BK 32
#define NT (EDIM / BK)
#define AH 0
#define WH 2048
#define BUF 6144

__global__ __launch_bounds__(256, 3) void gemm1_h1(
    const u16* __restrict__ Ahi,
    const u16* __restrict__ Whi,
    u16* __restrict__ h1H)
{
    __shared__ float smf[9216];                 // 36KB: 3x12KB staging
    u16* stage = (u16*)smf;

    const int bid = blockIdx.x;
    const int loc = bid >> 3;
    const int by  = (bid & 7) * 8 + (loc & 7);
    const int bx  = loc >> 3;
    const int row0 = by * BM, col0 = bx * BN;

    const int tid  = threadIdx.x;
    const int wave = tid >> 6, lane = tid & 63;
    const int wn   = wave;
    const int lrow = lane & 15, kgrp = lane >> 4;

    const int srr = lane >> 2;
    const int kcs = (((lane & 3) ^ ((lane >> 3) & 3)) << 3);
    const size_t aoff = (size_t)(row0 + wave * 16 + srr) * EDIM + kcs;
    const size_t w0   = (size_t)(col0 + wave * 32 + srr) * EDIM + kcs;
    const size_t w1   = w0 + (size_t)16 * EDIM;

    f32x4 acc[4][2];
    const f32x4 zero = {0.f, 0.f, 0.f, 0.f};
#pragma unroll
    for (int m = 0; m < 4; ++m)
#pragma unroll
        for (int n = 0; n < 2; ++n) acc[m][n] = zero;

    auto STAGE = [&](int k0, int b) {
        u16* lb = stage + b * BUF;
        gld16(Ahi + aoff + k0, lb + AH + wave * 512);
        gld16(Whi + w0 + k0, lb + WH + wave * 1024);
        gld16(Whi + w1 + k0, lb + WH + wave * 1024 + 512);
    };

    auto COMPUTE = [&](int b) {
        const u16* lb = stage + b * BUF;
        half8 ah[4], bh[2];
#pragma unroll
        for (int n = 0; n < 2; ++n) {
            const int c = wn * 32 + n * 16 + lrow;
            const int s = kgrp ^ ((c >> 1) & 3);
            bh[n] = *(const half8*)(lb + WH + c * 32 + s * 8);
        }
#pragma unroll
        for (int m = 0; m < 4; ++m) {
            const int r = m * 16 + lrow;
            const int s = kgrp ^ ((r >> 1) & 3);
            ah[m] = *(const half8*)(lb + AH + r * 32 + s * 8);
        }
#pragma unroll
        for (int m = 0; m < 4; ++m)
#pragma unroll
            for (int n = 0; n < 2; ++n)
                acc[m][n] = __builtin_amdgcn_mfma_f32_16x16x32_f16(ah[m], bh[n], acc[m][n], 0, 0, 0);
    };

    STAGE(0, 0);
    STAGE(BK, 1);
    int cc = 0, cs = 2;
    for (int t = 0; t < NT - 2; ++t) {
        STAGE((t + 2) * BK, cs);
        asm volatile("s_waitcnt vmcnt(6)" ::: "memory");
        __builtin_amdgcn_s_barrier();
        __builtin_amdgcn_sched_barrier(0);
        COMPUTE(cc);
        __builtin_amdgcn_s_barrier();
        cc = (cc == 2) ? 0 : cc + 1;
        cs = (cs == 2) ? 0 : cs + 1;
    }
    asm volatile("s_waitcnt vmcnt(3)" ::: "memory");
    __builtin_amdgcn_s_barrier();
    __builtin_amdgcn_sched_barrier(0);
    COMPUTE(cc);
    cc = (cc == 2) ? 0 : cc + 1;
    asm volatile("s_waitcnt vmcnt(0)" ::: "memory");
    __builtin_amdgcn_s_barrier();
    __builtin_amdgcn_sched_barrier(0);
    COMPUTE(cc);

    // epilogue: h1H[b][k][s] fp16 straight from acc, ushort4 along s.
#pragma unroll
    for (int n = 0; n < 2; ++n) {
        const int col = col0 + wn * 32 + n * 16 + lrow;
        u16* base = h1H + ((size_t)by * HDIM + col) * 64 + kgrp * 4;
#pragma unroll
        for (int m = 0; m < 4; ++m) {
            ushort4v v;
#pragma unroll
            for (int j = 0; j < 4; ++j) v[j] = f2h_bits(acc[m][n][j]);
            *(ushort4v*)(base + m * 16) = v;
        }
    }
}

// ---- LIF: 4-way sequence split, fp16 input -------------------------------
__global__ __launch_bounds__(256) void lif_count(
    const u16* __restrict__ h1H,
    const float* __restrict__ bias1,
    const float* __restrict__ pthr, const float* __restrict__ pleak,
    float* __restrict__ cnt)
{
    __shared__ float sm[4][64];
    const int tid  = threadIdx.x;
    const int q    = tid >> 6;            // wave = sequence quarter
    const int lane = tid & 63;
    const int neuron = blockIdx.x * 64 + lane;
    const float thr = pthr[0];
    const float lk  = pleak[0];
    const float b1v = bias1[neuron & (HDIM - 1)];
    const u16* row = h1H + (size_t)neuron * 64;

    float mem = 0.f, c = 0.f;
    const int w0 = q * 16;                // first counted word
    if (q > 0) {
        // warmup: 8 words, uncounted
        ushort8 v = *(const ushort8*)(row + w0 - 8);
#pragma unroll
        for (int u = 0; u < 8; ++u) {
            const float x = h2f(v[u]) + b1v;
#pragma unroll
            for (int t = 0; t < TSTEPS; ++t) {
                mem = lk * mem + x;
                if (mem > thr) mem -= thr;
            }
        }
    }
#pragma unroll
    for (int g = 0; g < 2; ++g) {         // counted: 2 x 8 words
        ushort8 v = *(const ushort8*)(row + w0 + g * 8);
#pragma unroll
        for (int u = 0; u < 8; ++u) {
            const float x = h2f(v[u]) + b1v;
#pragma unroll
            for (int t = 0; t < TSTEPS; ++t) {
                mem = lk * mem + x;
                if (mem > thr) { c += 1.f; mem -= thr; }
            }
        }
    }
    sm[q][lane] = c;
    __syncthreads();
    if (tid < 64)
        cnt[(size_t)blockIdx.x * 64 + tid] =
            sm[0][tid] + sm[1][tid] + sm[2][tid] + sm[3][tid];
}

// ---- GEMM2: K-split partials, 64-col tiles (256 blocks) ------------------
__global__ __launch_bounds__(256) void gemm2_partial(
    const float* __restrict__ cnt,
    const float* __restrict__ W2,
    float* __restrict__ part)
{
    __shared__ float As[32][68];
    __shared__ float Bs[32][68];

    const int tid   = threadIdx.x;
    const int col0  = blockIdx.x * 64;
    const int kc    = blockIdx.y;
    const int kbase = kc * 64;

    const int lr = tid >> 3;
    const int lc = (tid & 7) * 4;
    const int tm = (tid >> 4) * 4;
    const int tn = (tid & 15) * 4;

    float acc[4][4];
#pragma unroll
    for (int i = 0; i < 4; ++i)
#pragma unroll
        for (int j = 0; j < 4; ++j) acc[i][j] = 0.f;

    for (int kt = 0; kt < 2; ++kt) {
        const int k0 = kbase + kt * 32;
#pragma unroll
        for (int p = 0; p < 2; ++p) {
            int r = p * 32 + lr;
            float4 v = *(const float4*)(cnt + (size_t)r * HDIM + k0 + lc);
            As[lc + 0][r] = v.x; As[lc + 1][r] = v.y;
            As[lc + 2][r] = v.z; As[lc + 3][r] = v.w;
        }
#pragma unroll
        for (int p = 0; p < 2; ++p) {
            int r = p * 32 + lr;
            float4 v = *(const float4*)(W2 + (size_t)(col0 + r) * HDIM + k0 + lc);
            Bs[lc + 0][r] = v.x; Bs[lc + 1][r] = v.y;
            Bs[lc + 2][r] = v.z; Bs[lc + 3][r] = v.w;
        }
        __syncthreads();
#pragma unroll 8
        for (int k = 0; k < 32; ++k) {
            float4 a  = *(const float4*)&As[k][tm];
            float4 bb = *(const float4*)&Bs[k][tn];
            float av[4] = {a.x, a.y, a.z, a.w};
            float bv[4] = {bb.x, bb.y, bb.z, bb.w};
#pragma unroll
            for (int i = 0; i < 4; ++i)
#pragma unroll
                for (int j = 0; j < 4; ++j)
                    acc[i][j] += av[i] * bv[j];
        }
        __syncthreads();
    }

#pragma unroll
    for (int i = 0; i < 4; ++i) {
        float* prow = part + (size_t)kc * (BATCH * HDIM) + (size_t)(tm + i) * HDIM + col0;
        float4 o;
        o.x = acc[i][0]; o.y = acc[i][1]; o.z = acc[i][2]; o.w = acc[i][3];
        *(float4*)(prow + tn) = o;
    }
}

// ---- final reduce: out = (sum_kc part + 640*b2) / 64 ----------------------
__global__ __launch_bounds__(256) void reduce_out(
    const float* __restrict__ part,
    const float* __restrict__ b2,
    float* __restrict__ out)
{
    const int i = blockIdx.x * 256 + threadIdx.x;
    float s = 0.f;
#pragma unroll
    for (int kc = 0; kc < KSPLIT; ++kc)
        s += part[(size_t)kc * (BATCH * HDIM) + i];
    const int h = i & (HDIM - 1);
    out[i] = (s + (float)(SEQ * TSTEPS) * b2[h]) * (1.0f / (float)BATCH);
}

extern "C" void kernel_launch(void* const* d_in, const int* in_sizes, int n_in,
                              void* d_out, int out_size, void* d_ws, size_t ws_size,
                              hipStream_t stream)
{
    (void)in_sizes; (void)n_in; (void)out_size; (void)ws_size;

    const int*   idx  = (const int*)d_in[0];
    const float* emb  = (const float*)d_in[1];
    const float* W1   = (const float*)d_in[2];
    const float* b1   = (const float*)d_in[3];
    const float* W2   = (const float*)d_in[4];
    const float* b2   = (const float*)d_in[5];
    const float* thr  = (const float*)d_in[6];
    const float* leak = (const float*)d_in[7];
    float* out = (float*)d_out;

    char* ws = (char*)d_ws;
    float* part = (float*)ws;                                        // 4 MB
    float* cnt  = (float*)(ws + (size_t)KSPLIT * BATCH * HDIM * 4);  // 256 KB
    u16*   h1H  = (u16*)(cnt + (size_t)BATCH * HDIM);                // 8 MB
    u16* ahi = h1H + (size_t)NROW * HDIM;                            // 8 MB
    u16* whi = ahi + (size_t)NROW * EDIM;                            // 2 MB

    split_pack<<<dim3((NROW + HDIM) * 128 / 256), 256, 0, stream>>>(
        emb, W1, idx, ahi, whi);

    gemm1_h1<<<dim3((NROW / BM) * (HDIM / BN)), 256, 0, stream>>>(
        ahi, whi, h1H);

    lif_count<<<dim3(BATCH * HDIM / 64), 256, 0, stream>>>(
        h1H, b1, thr, leak, cnt);

    gemm2_partial<<<dim3(HDIM / 64, KSPLIT), 256, 0, stream>>>(cnt, W2, part);

    reduce_out<<<dim3((BATCH * HDIM) / 256), 256, 0, stream>>>(part, b2, out);
}